// Round 1
// baseline (216.091 us; speedup 1.0000x reference)
//
#include <hip/hip_runtime.h>

#define LSEQ 8192
#define CH   256

typedef __attribute__((ext_vector_type(8))) short short8;
typedef __attribute__((ext_vector_type(4))) float f32x4;

__device__ inline short f2bf(float f) {
  union { float f; unsigned u; } v; v.f = f;
  unsigned r = v.u + 0x7fffu + ((v.u >> 16) & 1u);
  return (short)(r >> 16);
}
__device__ inline float bf2f(short s) {
  union { unsigned u; float f; } v; v.u = ((unsigned)(unsigned short)s) << 16;
  return v.f;
}
__device__ inline short8 cvt8(float4 a, float4 b) {
  short8 v;
  v[0] = f2bf(a.x); v[1] = f2bf(a.y); v[2] = f2bf(a.z); v[3] = f2bf(a.w);
  v[4] = f2bf(b.x); v[5] = f2bf(b.y); v[6] = f2bf(b.z); v[7] = f2bf(b.w);
  return v;
}
__device__ inline f32x4 mfma16(short8 a, short8 b, f32x4 c) {
  return __builtin_amdgcn_mfma_f32_16x16x32_bf16(a, b, c, 0, 0, 0);
}

// ---------------------------------------------------------------------------
// Kernel 1: QKV projection.  y = x @ W^T + b  via bf16 MFMA.
//   m=0 -> Qb[row][col] = y * (1/L)   (prescale folds the attn /L)
//   m=1 -> Kb[row][col] = y
//   m=2 -> VTb[col][row] = y          (transposed for PV B-frag reads)
// Block: 256 thr (4 waves), covers 64 rows x 64 cols. grid = (128*4, 3).
// ---------------------------------------------------------------------------
__global__ __launch_bounds__(256) void qkv_kernel(
    const float* __restrict__ x,
    const float* __restrict__ Wq, const float* __restrict__ bq,
    const float* __restrict__ Wk, const float* __restrict__ bk,
    const float* __restrict__ Wv, const float* __restrict__ bv,
    short* __restrict__ Qb, short* __restrict__ Kb, short* __restrict__ VTb)
{
  const int m = blockIdx.y;
  const float* W = (m == 0) ? Wq : ((m == 1) ? Wk : Wv);
  const float* bp = (m == 0) ? bq : ((m == 1) ? bk : bv);
  const int rb = blockIdx.x >> 2;
  const int cb = blockIdx.x & 3;
  const int row0 = rb * 64, col0 = cb * 64;

  // W tile: 64 out-cols x 256 d, bf16, chunk-swizzled (c_phys = c_log ^ (r&7))
  __shared__ __align__(16) short wt[64 * 256];

  const int tid = threadIdx.x;
#pragma unroll
  for (int i = 0; i < 8; ++i) {
    int g = i * 256 + tid;            // 0..2047 chunks of 16B
    int r = g >> 5, cl = g & 31;
    const float4* src = (const float4*)(W + (col0 + r) * CH + cl * 8);
    short8 v = cvt8(src[0], src[1]);
    *(short8*)(&wt[r * 256 + (cl ^ (r & 7)) * 8]) = v;
  }
  __syncthreads();

  const int wid = tid >> 6, lane = tid & 63;
  const int l15 = lane & 15, h = lane >> 4;
  const int wrow0 = row0 + wid * 16;

  f32x4 acc[4] = {};
#pragma unroll
  for (int kd = 0; kd < 8; ++kd) {
    const float4* xs = (const float4*)(x + (wrow0 + l15) * CH + kd * 32 + h * 8);
    short8 af = cvt8(xs[0], xs[1]);
#pragma unroll
    for (int nf = 0; nf < 4; ++nf) {
      int r = nf * 16 + l15;
      int cl = kd * 4 + h;
      short8 bf = *(const short8*)(&wt[r * 256 + (cl ^ (r & 7)) * 8]);
      acc[nf] = mfma16(af, bf, acc[nf]);
    }
  }

  // C/D layout: col = lane&15, row = (lane>>4)*4 + reg   [m89-verified]
#pragma unroll
  for (int nf = 0; nf < 4; ++nf) {
    int col = col0 + nf * 16 + l15;
    float bias = bp[col];
#pragma unroll
    for (int r = 0; r < 4; ++r) {
      int row = wrow0 + h * 4 + r;
      float y = acc[nf][r] + bias;
      if (m == 0)      Qb[row * CH + col] = f2bf(y * (1.0f / 8192.0f));
      else if (m == 1) Kb[row * CH + col] = f2bf(y);
      else             VTb[(size_t)col * LSEQ + row] = f2bf(y);
    }
  }
}

// ---------------------------------------------------------------------------
// Kernel: column sums of V (from bf16 VT), fp32.  colsum[d] = sum_i V[i][d]
// ---------------------------------------------------------------------------
__global__ __launch_bounds__(256) void colsum_kernel(
    const short* __restrict__ VTb, float* __restrict__ colsum)
{
  int d = blockIdx.x, tid = threadIdx.x;
  const short8* row = (const short8*)(VTb + (size_t)d * LSEQ);
  float s = 0.f;
  for (int i = tid; i < LSEQ / 8; i += 256) {
    short8 v = row[i];
#pragma unroll
    for (int j = 0; j < 8; ++j) s += bf2f(v[j]);
  }
  __shared__ float red[256];
  red[tid] = s;
  __syncthreads();
  for (int st = 128; st > 0; st >>= 1) {
    if (tid < st) red[tid] += red[tid + st];
    __syncthreads();
  }
  if (tid == 0) colsum[d] = red[0];
}

// ---------------------------------------------------------------------------
// Kernel 2: fused  Opart = expm1(Q K^T) @ V  (key-split), z = sum expm1.
// Block: 256 thr (4 waves x 16 q-rows = BQ 64). BK=64 key tiles.
// LDS: K tile [64][256] bf16 (32KB) + VT tile [256][64] bf16 (32KB), both
// XOR-chunk-swizzled (G4 fix for 512B/128B row strides), + per-warp P (8KB).
// blockIdx % ksplit = key-slice -> lands per-XCD (L2-resident K/VT slice).
// ---------------------------------------------------------------------------
__global__ __launch_bounds__(256) void attn_kernel(
    const short* __restrict__ Qb, const short* __restrict__ Kb,
    const short* __restrict__ VTb, float* __restrict__ Opart,
    float* __restrict__ zsum, int ksplit, int keys_per_split)
{
  __shared__ __align__(16) short kt[64 * 256];
  __shared__ __align__(16) short vt[256 * 64];
  __shared__ __align__(16) short pt[4][16 * 64];
  __shared__ float zred[4];

  const int bid = blockIdx.x;
  const int ksl = bid % ksplit;
  const int rb = bid / ksplit;
  const int row0 = rb * 64;
  const int key0 = ksl * keys_per_split;
  const int ntiles = keys_per_split >> 6;

  const int tid = threadIdx.x, wid = tid >> 6, lane = tid & 63;
  const int l15 = lane & 15, h = lane >> 4;

  // Preload Q fragments: A-frag lane layout row=lane&15, k=(lane>>4)*8+j
  short8 qf[8];
  {
    const short* qrow = Qb + (size_t)(row0 + wid * 16 + l15) * CH;
#pragma unroll
    for (int kd = 0; kd < 8; ++kd)
      qf[kd] = *(const short8*)(qrow + kd * 32 + h * 8);
  }

  f32x4 oacc[16] = {};
  float zloc = 0.f;

  for (int t = 0; t < ntiles; ++t) {
    const int kbase = key0 + t * 64;
    __syncthreads();  // previous tile's LDS reads done before overwrite
    // stage K tile (2048 x 16B chunks), swizzled write
#pragma unroll
    for (int i = 0; i < 8; ++i) {
      int g = i * 256 + tid;
      int r = g >> 5, cl = g & 31;
      short8 v = *(const short8*)(Kb + (size_t)(kbase + r) * CH + cl * 8);
      *(short8*)(&kt[r * 256 + (cl ^ (r & 7)) * 8]) = v;
    }
    // stage VT tile (2048 chunks; row d has 8 chunks of 8 keys)
#pragma unroll
    for (int i = 0; i < 8; ++i) {
      int g = i * 256 + tid;
      int d = g >> 3, cl = g & 7;
      short8 v = *(const short8*)(VTb + (size_t)d * LSEQ + kbase + cl * 8);
      *(short8*)(&vt[d * 64 + (cl ^ (d & 7)) * 8]) = v;
    }
    __syncthreads();

    // S = Q K^T   (prescaled: Qb already holds q/L)
    f32x4 sacc[4] = {};
#pragma unroll
    for (int kd = 0; kd < 8; ++kd) {
#pragma unroll
      for (int nf = 0; nf < 4; ++nf) {
        int r = nf * 16 + l15;
        int cl = kd * 4 + h;
        short8 bf = *(const short8*)(&kt[r * 256 + (cl ^ (r & 7)) * 8]);
        sacc[nf] = mfma16(qf[kd], bf, sacc[nf]);
      }
    }

    // P = expm1(S) -> bf16 in per-warp LDS; accumulate z
    short* pw = &pt[wid][0];
#pragma unroll
    for (int nf = 0; nf < 4; ++nf) {
#pragma unroll
      for (int r = 0; r < 4; ++r) {
        float s = sacc[nf][r];
        float p = __expf(s) - 1.0f;   // |s| ~ 2e-3: expm1 via exp-1 is fine
        zloc += p;
        int q = h * 4 + r;
        int key = nf * 16 + l15;
        int cp = (key >> 3) ^ (q & 7);
        pw[q * 64 + cp * 8 + (key & 7)] = f2bf(p);
      }
    }
    asm volatile("s_waitcnt lgkmcnt(0)" ::: "memory");

    // P fragments (A-operand of PV): row q = lane&15, keys kk*32 + h*8 + j
    short8 pf[2];
#pragma unroll
    for (int kk = 0; kk < 2; ++kk) {
      int cp = (kk * 4 + h) ^ (l15 & 7);
      pf[kk] = *(const short8*)(&pw[l15 * 64 + cp * 8]);
    }

    // O += P @ V   (B-frag: VT row d = nf2*16 + lane&15, contiguous keys)
#pragma unroll
    for (int nf2 = 0; nf2 < 16; ++nf2) {
#pragma unroll
      for (int kk = 0; kk < 2; ++kk) {
        int d = nf2 * 16 + l15;
        int cp = (kk * 4 + h) ^ (d & 7);
        short8 bf = *(const short8*)(&vt[d * 64 + cp * 8]);
        oacc[nf2] = mfma16(pf[kk], bf, oacc[nf2]);
      }
    }
  }

  // write partial O (disjoint per (rb, ksl) -> plain stores)
  float* op = Opart + ((size_t)ksl * LSEQ + row0 + wid * 16) * CH;
#pragma unroll
  for (int nf2 = 0; nf2 < 16; ++nf2) {
    int col = nf2 * 16 + l15;
#pragma unroll
    for (int r = 0; r < 4; ++r)
      op[(h * 4 + r) * CH + col] = oacc[nf2][r];
  }

  // z: wave reduce -> block reduce -> one atomic
#pragma unroll
  for (int off = 32; off > 0; off >>= 1) zloc += __shfl_down(zloc, off, 64);
  if (lane == 0) zred[wid] = zloc;
  __syncthreads();
  if (tid == 0) atomicAdd(zsum, zred[0] + zred[1] + zred[2] + zred[3]);
}

// ---------------------------------------------------------------------------
// Kernel 3: O = (colsum(V) + sum_k Opart[k]) / (L^2 + zsum)
// ---------------------------------------------------------------------------
__global__ __launch_bounds__(256) void final_kernel(
    const float* __restrict__ Opart, const float* __restrict__ colsum,
    const float* __restrict__ zsum, float* __restrict__ out, int ksplit)
{
  size_t idx = (size_t)blockIdx.x * 256 + threadIdx.x;  // float4 index
  float inv = 1.0f / (8192.0f * 8192.0f + *zsum);
  int col0 = (int)((idx * 4) & (CH - 1));
  float4 acc = *(const float4*)(colsum + col0);
  for (int k = 0; k < ksplit; ++k) {
    float4 p = *(const float4*)(Opart + (size_t)k * LSEQ * CH + idx * 4);
    acc.x += p.x; acc.y += p.y; acc.z += p.z; acc.w += p.w;
  }
  float4 o;
  o.x = acc.x * inv; o.y = acc.y * inv; o.z = acc.z * inv; o.w = acc.w * inv;
  *(float4*)(out + idx * 4) = o;
}

// ---------------------------------------------------------------------------
extern "C" void kernel_launch(void* const* d_in, const int* in_sizes, int n_in,
                              void* d_out, int out_size, void* d_ws, size_t ws_size,
                              hipStream_t stream) {
  const float* x  = (const float*)d_in[0];
  const float* Wq = (const float*)d_in[1];
  const float* bq = (const float*)d_in[2];
  const float* Wk = (const float*)d_in[3];
  const float* bk = (const float*)d_in[4];
  const float* Wv = (const float*)d_in[5];
  const float* bv = (const float*)d_in[6];
  float* out = (float*)d_out;

  // workspace layout
  char* ws = (char*)d_ws;
  short* Qb  = (short*)ws;                                   // 4 MB
  short* Kb  = Qb + (size_t)LSEQ * CH;                       // 4 MB
  short* VTb = Kb + (size_t)LSEQ * CH;                       // 4 MB
  float* colsum = (float*)(VTb + (size_t)CH * LSEQ);         // 1 KB
  float* zsum   = (float*)((char*)colsum + 2048);            // 4 B
  float* Opart  = (float*)((char*)ws + 12u * 1024 * 1024 + 4096);
  const size_t fixed = 12u * 1024 * 1024 + 4096;
  const size_t part_bytes = (size_t)LSEQ * CH * sizeof(float);  // 8 MB

  int ksplit = 8;  // key-split: low bits of blockIdx -> XCD -> L2-resident slice
  while (ksplit > 1 && fixed + (size_t)ksplit * part_bytes > ws_size) ksplit >>= 1;

  hipMemsetAsync(zsum, 0, sizeof(float), stream);

  qkv_kernel<<<dim3(512, 3), 256, 0, stream>>>(x, Wq, bq, Wk, bk, Wv, bv,
                                               Qb, Kb, VTb);
  colsum_kernel<<<CH, 256, 0, stream>>>(VTb, colsum);
  attn_kernel<<<(LSEQ / 64) * ksplit, 256, 0, stream>>>(
      Qb, Kb, VTb, Opart, zsum, ksplit, LSEQ / ksplit);
  final_kernel<<<(LSEQ * CH / 4) / 256, 256, 0, stream>>>(
      Opart, colsum, zsum, out, ksplit);
}

// Round 2
// 161.392 us; speedup vs baseline: 1.3389x; 1.3389x over previous
//
#include <hip/hip_runtime.h>

#define LSEQ 8192
#define CH   256

typedef __attribute__((ext_vector_type(8))) short short8;
typedef __attribute__((ext_vector_type(4))) float f32x4;
typedef __attribute__((ext_vector_type(4))) unsigned short ushort4v;
typedef unsigned int u32;

__device__ inline short f2bf(float f) {
  union { float f; unsigned u; } v; v.f = f;
  unsigned r = v.u + 0x7fffu + ((v.u >> 16) & 1u);
  return (short)(r >> 16);
}
__device__ inline float bf2f(unsigned short s) {
  union { unsigned u; float f; } v; v.u = ((unsigned)s) << 16;
  return v.f;
}
__device__ inline short8 cvt8(float4 a, float4 b) {
  short8 v;
  v[0] = f2bf(a.x); v[1] = f2bf(a.y); v[2] = f2bf(a.z); v[3] = f2bf(a.w);
  v[4] = f2bf(b.x); v[5] = f2bf(b.y); v[6] = f2bf(b.z); v[7] = f2bf(b.w);
  return v;
}
__device__ inline f32x4 mfma16(short8 a, short8 b, f32x4 c) {
  return __builtin_amdgcn_mfma_f32_16x16x32_bf16(a, b, c, 0, 0, 0);
}
// async global -> LDS, 16B per lane; dest = uniform base + lane*16
__device__ __forceinline__ void gload16(const void* g, void* l) {
  __builtin_amdgcn_global_load_lds(
      (const __attribute__((address_space(1))) u32*)g,
      (__attribute__((address_space(3))) u32*)l, 16, 0, 0);
}

// ---------------------------------------------------------------------------
// Kernel 1: QKV projection.  y = x @ W^T + b  via bf16 MFMA.
//   m=0 -> Qb[row][col] = y * (1/L)   (prescale folds the attn /L)
//   m=1 -> Kb[row][col] = y
//   m=2 -> VTb[col][row] = y          (transposed for PV B-frag reads)
// ---------------------------------------------------------------------------
__global__ __launch_bounds__(256) void qkv_kernel(
    const float* __restrict__ x,
    const float* __restrict__ Wq, const float* __restrict__ bq,
    const float* __restrict__ Wk, const float* __restrict__ bk,
    const float* __restrict__ Wv, const float* __restrict__ bv,
    short* __restrict__ Qb, short* __restrict__ Kb, short* __restrict__ VTb)
{
  const int m = blockIdx.y;
  const float* W = (m == 0) ? Wq : ((m == 1) ? Wk : Wv);
  const float* bp = (m == 0) ? bq : ((m == 1) ? bk : bv);
  const int rb = blockIdx.x >> 2;
  const int cb = blockIdx.x & 3;
  const int row0 = rb * 64, col0 = cb * 64;

  __shared__ __align__(16) short wt[64 * 256];

  const int tid = threadIdx.x;
#pragma unroll
  for (int i = 0; i < 8; ++i) {
    int g = i * 256 + tid;            // chunk of 16B
    int r = g >> 5, cl = g & 31;
    const float4* src = (const float4*)(W + (col0 + r) * CH + cl * 8);
    short8 v = cvt8(src[0], src[1]);
    *(short8*)(&wt[r * 256 + (cl ^ (r & 7)) * 8]) = v;
  }
  __syncthreads();

  const int wid = tid >> 6, lane = tid & 63;
  const int l15 = lane & 15, h = lane >> 4;
  const int wrow0 = row0 + wid * 16;

  f32x4 acc[4] = {};
#pragma unroll
  for (int kd = 0; kd < 8; ++kd) {
    const float4* xs = (const float4*)(x + (wrow0 + l15) * CH + kd * 32 + h * 8);
    short8 af = cvt8(xs[0], xs[1]);
#pragma unroll
    for (int nf = 0; nf < 4; ++nf) {
      int r = nf * 16 + l15;
      int cl = kd * 4 + h;
      short8 bf = *(const short8*)(&wt[r * 256 + (cl ^ (r & 7)) * 8]);
      acc[nf] = mfma16(af, bf, acc[nf]);
    }
  }

  // C/D layout: col = lane&15, row = (lane>>4)*4 + reg
#pragma unroll
  for (int nf = 0; nf < 4; ++nf) {
    int col = col0 + nf * 16 + l15;
    float bias = bp[col];
#pragma unroll
    for (int r = 0; r < 4; ++r) {
      int row = wrow0 + h * 4 + r;
      float y = acc[nf][r] + bias;
      if (m == 0)      Qb[row * CH + col] = f2bf(y * (1.0f / 8192.0f));
      else if (m == 1) Kb[row * CH + col] = f2bf(y);
      else             VTb[(size_t)col * LSEQ + row] = f2bf(y);
    }
  }
}

// ---------------------------------------------------------------------------
// colsum[d] = sum_i V[i][d]  (from bf16 VT), fp32
// ---------------------------------------------------------------------------
__global__ __launch_bounds__(256) void colsum_kernel(
    const short* __restrict__ VTb, float* __restrict__ colsum)
{
  int d = blockIdx.x, tid = threadIdx.x;
  const short8* row = (const short8*)(VTb + (size_t)d * LSEQ);
  float s = 0.f;
  for (int i = tid; i < LSEQ / 8; i += 256) {
    short8 v = row[i];
#pragma unroll
    for (int j = 0; j < 8; ++j) s += bf2f((unsigned short)v[j]);
  }
  __shared__ float red[256];
  red[tid] = s;
  __syncthreads();
  for (int st = 128; st > 0; st >>= 1) {
    if (tid < st) red[tid] += red[tid + st];
    __syncthreads();
  }
  if (tid == 0) colsum[d] = red[0];
}

// ---------------------------------------------------------------------------
// Kernel 2: Opart = expm1(Q K^T) @ V  (key-split), z = sum expm1.
// BQ=128 (4 waves x 32 q-rows), BK=64. LDS: K[64][256] + VT[256][64], both
// chunk-XOR-swizzled, staged via global_load_lds with pre-swizzled source.
// S computed transposed (mfma(K,Q)); P redistributed in-register via
// ds_bpermute (no LDS P buffer, no scalar writes).
// ---------------------------------------------------------------------------
__global__ __launch_bounds__(256, 2) void attn_kernel(
    const short* __restrict__ Qb, const short* __restrict__ Kb,
    const short* __restrict__ VTb, unsigned short* __restrict__ Opart,
    float* __restrict__ zsum, int ksplit, int keys_per_split)
{
  __shared__ __align__(16) short kt[64 * 256];   // 32KB [key][d]
  __shared__ __align__(16) short vt[256 * 64];   // 32KB [d][key]

  const int bid = blockIdx.x;
  const int ksl = bid % ksplit;                  // low bits -> XCD slice
  const int rb  = bid / ksplit;
  const int row0 = rb * 128;
  const int key0 = ksl * keys_per_split;
  const int ntiles = keys_per_split >> 6;

  const int tid = threadIdx.x, wid = tid >> 6, lane = tid & 63;
  const int l15 = lane & 15, h = lane >> 4;
  const int wq0 = row0 + wid * 32;

  // Q fragments (B-operand of S^T mfma): q = wq0 + nq*16 + l15, d = kd*32+h*8+j
  short8 qf[2][8];
#pragma unroll
  for (int nq = 0; nq < 2; ++nq)
#pragma unroll
    for (int kd = 0; kd < 8; ++kd)
      qf[nq][kd] = *(const short8*)(Qb + (size_t)(wq0 + nq * 16 + l15) * CH + kd * 32 + h * 8);

  f32x4 oacc[2][16] = {};
  float zloc = 0.f;

  // bpermute source-lane addresses (byte = lane*4)
  const int addr0 = (l15 + ((h & 1) << 5)) << 2;   // lane l15 + 32*(h&1)
  const int addr1 = addr0 + 64;                    // +16 lanes
  const int hs = h >> 1;                           // source-register selector

  for (int t = 0; t < ntiles; ++t) {
    const int kbase = key0 + t * 64;
    __syncthreads();   // prior tile's LDS reads complete before DMA overwrite
    // stage K tile: phys chunk g holds K[r][(clp^(r&7))*8..] (src pre-swizzled)
#pragma unroll
    for (int i = 0; i < 8; ++i) {
      int g = i * 256 + tid;
      int r = g >> 5, clp = g & 31;
      const short* src = Kb + (size_t)(kbase + r) * CH + (clp ^ (r & 7)) * 8;
      gload16(src, &kt[(i * 256 + wid * 64) * 8]);
    }
    // stage VT tile: phys chunk g holds VT[d][kbase + (clp^(d&7))*8..]
#pragma unroll
    for (int i = 0; i < 8; ++i) {
      int g = i * 256 + tid;
      int d = g >> 3, clp = g & 7;
      const short* src = VTb + (size_t)d * LSEQ + kbase + (clp ^ (d & 7)) * 8;
      gload16(src, &vt[(i * 256 + wid * 64) * 8]);
    }
    __syncthreads();   // vmcnt(0) drain + barrier: tiles ready

#pragma unroll
    for (int kk = 0; kk < 2; ++kk) {           // 32-key chunk
      // S^T chunk: sacc[mk2][nq] = S[q = nq*16+l15][key = (2kk+mk2)*16 + h*4+r]
      f32x4 sacc[2][2] = {};
#pragma unroll
      for (int kd = 0; kd < 8; ++kd) {
#pragma unroll
        for (int mk2 = 0; mk2 < 2; ++mk2) {
          int key = (kk * 2 + mk2) * 16 + l15;
          short8 kf = *(const short8*)(&kt[key * CH + (((kd * 4 + h) ^ (l15 & 7)) * 8)]);
          sacc[mk2][0] = mfma16(kf, qf[0][kd], sacc[mk2][0]);
          sacc[mk2][1] = mfma16(kf, qf[1][kd], sacc[mk2][1]);
        }
      }
      // P = expm1(S): exp + pack to bf16 pairs
      u32 pk[2][2][2];
#pragma unroll
      for (int mk2 = 0; mk2 < 2; ++mk2)
#pragma unroll
        for (int nq = 0; nq < 2; ++nq) {
          float p0 = __expf(sacc[mk2][nq][0]) - 1.0f;
          float p1 = __expf(sacc[mk2][nq][1]) - 1.0f;
          float p2 = __expf(sacc[mk2][nq][2]) - 1.0f;
          float p3 = __expf(sacc[mk2][nq][3]) - 1.0f;
          zloc += (p0 + p1) + (p2 + p3);
          pk[mk2][nq][0] = (u32)(unsigned short)f2bf(p0) | ((u32)(unsigned short)f2bf(p1) << 16);
          pk[mk2][nq][1] = (u32)(unsigned short)f2bf(p2) | ((u32)(unsigned short)f2bf(p3) << 16);
        }
      // redistribute -> PA[nq]: element j = key kk*32 + h*8 + j (A-frag layout)
      short8 PA[2];
#pragma unroll
      for (int nq = 0; nq < 2; ++nq) {
        u32 a00 = (u32)__builtin_amdgcn_ds_bpermute(addr0, (int)pk[0][nq][0]);
        u32 a01 = (u32)__builtin_amdgcn_ds_bpermute(addr0, (int)pk[1][nq][0]);
        u32 a10 = (u32)__builtin_amdgcn_ds_bpermute(addr0, (int)pk[0][nq][1]);
        u32 a11 = (u32)__builtin_amdgcn_ds_bpermute(addr0, (int)pk[1][nq][1]);
        u32 a20 = (u32)__builtin_amdgcn_ds_bpermute(addr1, (int)pk[0][nq][0]);
        u32 a21 = (u32)__builtin_amdgcn_ds_bpermute(addr1, (int)pk[1][nq][0]);
        u32 a30 = (u32)__builtin_amdgcn_ds_bpermute(addr1, (int)pk[0][nq][1]);
        u32 a31 = (u32)__builtin_amdgcn_ds_bpermute(addr1, (int)pk[1][nq][1]);
        union { u32 u[4]; short8 s; } cv;
        cv.u[0] = hs ? a01 : a00;
        cv.u[1] = hs ? a11 : a10;
        cv.u[2] = hs ? a21 : a20;
        cv.u[3] = hs ? a31 : a30;
        PA[nq] = cv.s;
      }
      // O += P @ V  (B-frag: VT row d, keys kk*32 + h*8 + j)
#pragma unroll
      for (int nf2 = 0; nf2 < 16; ++nf2) {
        int d = nf2 * 16 + l15;
        short8 vf = *(const short8*)(&vt[d * 64 + (((kk * 4 + h) ^ (l15 & 7)) * 8)]);
        oacc[0][nf2] = mfma16(PA[0], vf, oacc[0][nf2]);
        oacc[1][nf2] = mfma16(PA[1], vf, oacc[1][nf2]);
      }
    }
  }

  // write partial O (bf16; disjoint per (rb, ksl))
  unsigned short* op = Opart + (size_t)ksl * LSEQ * CH;
#pragma unroll
  for (int nq = 0; nq < 2; ++nq)
#pragma unroll
    for (int nf2 = 0; nf2 < 16; ++nf2) {
      int col = nf2 * 16 + l15;
#pragma unroll
      for (int r = 0; r < 4; ++r) {
        int row = wq0 + nq * 16 + h * 4 + r;
        op[(size_t)row * CH + col] = (unsigned short)f2bf(oacc[nq][nf2][r]);
      }
    }

  // z: wave shuffle-reduce -> block reduce (reuse kt) -> one atomic per block
#pragma unroll
  for (int off = 32; off > 0; off >>= 1) zloc += __shfl_down(zloc, off, 64);
  __syncthreads();
  float* zr = (float*)kt;
  if (lane == 0) zr[wid] = zloc;
  __syncthreads();
  if (tid == 0) atomicAdd(zsum, (zr[0] + zr[1]) + (zr[2] + zr[3]));
}

// ---------------------------------------------------------------------------
// Kernel 3: O = (colsum(V) + sum_k Opart[k]) / (L^2 + zsum)
// ---------------------------------------------------------------------------
__global__ __launch_bounds__(256) void final_kernel(
    const unsigned short* __restrict__ Opart, const float* __restrict__ colsum,
    const float* __restrict__ zsum, float* __restrict__ out, int ksplit)
{
  size_t idx = (size_t)blockIdx.x * 256 + threadIdx.x;  // 4 outputs per thread
  float inv = 1.0f / (8192.0f * 8192.0f + *zsum);
  int col0 = (int)((idx * 4) & (CH - 1));
  float4 acc = *(const float4*)(colsum + col0);
  for (int k = 0; k < ksplit; ++k) {
    ushort4v p = *(const ushort4v*)(Opart + (size_t)k * LSEQ * CH + idx * 4);
    acc.x += bf2f(p[0]); acc.y += bf2f(p[1]);
    acc.z += bf2f(p[2]); acc.w += bf2f(p[3]);
  }
  float4 o;
  o.x = acc.x * inv; o.y = acc.y * inv; o.z = acc.z * inv; o.w = acc.w * inv;
  *(float4*)(out + idx * 4) = o;
}

// ---------------------------------------------------------------------------
extern "C" void kernel_launch(void* const* d_in, const int* in_sizes, int n_in,
                              void* d_out, int out_size, void* d_ws, size_t ws_size,
                              hipStream_t stream) {
  const float* x  = (const float*)d_in[0];
  const float* Wq = (const float*)d_in[1];
  const float* bq = (const float*)d_in[2];
  const float* Wk = (const float*)d_in[3];
  const float* bk = (const float*)d_in[4];
  const float* Wv = (const float*)d_in[5];
  const float* bv = (const float*)d_in[6];
  float* out = (float*)d_out;

  // workspace layout
  char* ws = (char*)d_ws;
  short* Qb  = (short*)ws;                                   // 4 MB
  short* Kb  = Qb + (size_t)LSEQ * CH;                       // 4 MB
  short* VTb = Kb + (size_t)LSEQ * CH;                       // 4 MB
  float* colsum = (float*)(VTb + (size_t)CH * LSEQ);         // 1 KB
  float* zsum   = (float*)((char*)colsum + 2048);            // 4 B
  unsigned short* Opart = (unsigned short*)((char*)ws + 12u * 1024 * 1024 + 4096);
  const size_t fixed = 12u * 1024 * 1024 + 4096;
  const size_t part_bytes = (size_t)LSEQ * CH * sizeof(unsigned short);  // 4 MB

  int ksplit = 8;  // key-split: blockIdx%8 -> XCD -> L2-resident K/VT slice
  while (ksplit > 1 && fixed + (size_t)ksplit * part_bytes > ws_size) ksplit >>= 1;

  hipMemsetAsync(zsum, 0, sizeof(float), stream);

  qkv_kernel<<<dim3(512, 3), 256, 0, stream>>>(x, Wq, bq, Wk, bk, Wv, bv,
                                               Qb, Kb, VTb);
  colsum_kernel<<<CH, 256, 0, stream>>>(VTb, colsum);
  attn_kernel<<<(LSEQ / 128) * ksplit, 256, 0, stream>>>(
      Qb, Kb, VTb, Opart, zsum, ksplit, LSEQ / ksplit);
  final_kernel<<<(LSEQ * CH / 4) / 256, 256, 0, stream>>>(
      Opart, colsum, zsum, out, ksplit);
}

// Round 3
// 124.329 us; speedup vs baseline: 1.7381x; 1.2981x over previous
//
#include <hip/hip_runtime.h>

#define LSEQ 8192
#define CH   256
#define BK   32          // keys per pipeline tile

typedef __attribute__((ext_vector_type(8))) short short8;
typedef __attribute__((ext_vector_type(4))) float f32x4;
typedef __attribute__((ext_vector_type(4))) unsigned short ushort4v;
typedef unsigned int u32;

__device__ inline short f2bf(float f) {
  union { float f; unsigned u; } v; v.f = f;
  unsigned r = v.u + 0x7fffu + ((v.u >> 16) & 1u);
  return (short)(r >> 16);
}
__device__ inline float bf2f(unsigned short s) {
  union { unsigned u; float f; } v; v.u = ((unsigned)s) << 16;
  return v.f;
}
__device__ inline short8 cvt8(float4 a, float4 b) {
  short8 v;
  v[0] = f2bf(a.x); v[1] = f2bf(a.y); v[2] = f2bf(a.z); v[3] = f2bf(a.w);
  v[4] = f2bf(b.x); v[5] = f2bf(b.y); v[6] = f2bf(b.z); v[7] = f2bf(b.w);
  return v;
}
__device__ inline f32x4 mfma16(short8 a, short8 b, f32x4 c) {
  return __builtin_amdgcn_mfma_f32_16x16x32_bf16(a, b, c, 0, 0, 0);
}
// async global -> LDS, 16B per lane; dest = wave-uniform base + lane*16
__device__ __forceinline__ void gload16(const void* g, void* l) {
  __builtin_amdgcn_global_load_lds(
      (const __attribute__((address_space(1))) u32*)g,
      (__attribute__((address_space(3))) u32*)l, 16, 0, 0);
}

// ---------------------------------------------------------------------------
// Kernel 1: QKV projection.  y = x @ W^T + b  via bf16 MFMA.
//   m=0 -> Qb[row][col] = y * (1/L)   (prescale folds the attn /L)
//   m=1 -> Kb[row][col] = y
//   m=2 -> VTb[col][row] = y          (transposed for PV B-frag reads)
// ---------------------------------------------------------------------------
__global__ __launch_bounds__(256) void qkv_kernel(
    const float* __restrict__ x,
    const float* __restrict__ Wq, const float* __restrict__ bq,
    const float* __restrict__ Wk, const float* __restrict__ bk,
    const float* __restrict__ Wv, const float* __restrict__ bv,
    short* __restrict__ Qb, short* __restrict__ Kb, short* __restrict__ VTb)
{
  const int m = blockIdx.y;
  const float* W = (m == 0) ? Wq : ((m == 1) ? Wk : Wv);
  const float* bp = (m == 0) ? bq : ((m == 1) ? bk : bv);
  const int rb = blockIdx.x >> 2;
  const int cb = blockIdx.x & 3;
  const int row0 = rb * 64, col0 = cb * 64;

  __shared__ __align__(16) short wt[64 * 256];

  const int tid = threadIdx.x;
#pragma unroll
  for (int i = 0; i < 8; ++i) {
    int g = i * 256 + tid;            // chunk of 16B
    int r = g >> 5, cl = g & 31;
    const float4* src = (const float4*)(W + (col0 + r) * CH + cl * 8);
    short8 v = cvt8(src[0], src[1]);
    *(short8*)(&wt[r * 256 + (cl ^ (r & 7)) * 8]) = v;
  }
  __syncthreads();

  const int wid = tid >> 6, lane = tid & 63;
  const int l15 = lane & 15, h = lane >> 4;
  const int wrow0 = row0 + wid * 16;

  f32x4 acc[4] = {};
#pragma unroll
  for (int kd = 0; kd < 8; ++kd) {
    const float4* xs = (const float4*)(x + (wrow0 + l15) * CH + kd * 32 + h * 8);
    short8 af = cvt8(xs[0], xs[1]);
#pragma unroll
    for (int nf = 0; nf < 4; ++nf) {
      int r = nf * 16 + l15;
      int cl = kd * 4 + h;
      short8 bf = *(const short8*)(&wt[r * 256 + (cl ^ (r & 7)) * 8]);
      acc[nf] = mfma16(af, bf, acc[nf]);
    }
  }

  // C/D layout: col = lane&15, row = (lane>>4)*4 + reg
#pragma unroll
  for (int nf = 0; nf < 4; ++nf) {
    int col = col0 + nf * 16 + l15;
    float bias = bp[col];
#pragma unroll
    for (int r = 0; r < 4; ++r) {
      int row = wrow0 + h * 4 + r;
      float y = acc[nf][r] + bias;
      if (m == 0)      Qb[row * CH + col] = f2bf(y * (1.0f / 8192.0f));
      else if (m == 1) Kb[row * CH + col] = f2bf(y);
      else             VTb[(size_t)col * LSEQ + row] = f2bf(y);
    }
  }
}

// ---------------------------------------------------------------------------
// colsum[d] = sum_i V[i][d]  (from bf16 VT), fp32
// ---------------------------------------------------------------------------
__global__ __launch_bounds__(256) void colsum_kernel(
    const short* __restrict__ VTb, float* __restrict__ colsum)
{
  int d = blockIdx.x, tid = threadIdx.x;
  const short8* row = (const short8*)(VTb + (size_t)d * LSEQ);
  float s = 0.f;
  for (int i = tid; i < LSEQ / 8; i += 256) {
    short8 v = row[i];
#pragma unroll
    for (int j = 0; j < 8; ++j) s += bf2f((unsigned short)v[j]);
  }
  __shared__ float red[256];
  red[tid] = s;
  __syncthreads();
  for (int st = 128; st > 0; st >>= 1) {
    if (tid < st) red[tid] += red[tid + st];
    __syncthreads();
  }
  if (tid == 0) colsum[d] = red[0];
}

// ---------------------------------------------------------------------------
// Kernel 2: Opart = expm1(Q K^T) @ V  (key-split), z = sum expm1.
// BQ=128 (4 waves x 32 q-rows), BK=32, double-buffered LDS (T3 2-phase),
// counted vmcnt(8) across raw s_barrier (T4), setprio around MFMA (T5).
// K tile [32][256] + VT tile [256][32] per buffer, chunk-XOR-swizzled,
// staged via global_load_lds with pre-swizzled global source.
// S computed transposed (mfma(K,Q)); P redistributed in-register via
// ds_bpermute.
// ---------------------------------------------------------------------------
__global__ __launch_bounds__(256, 2) void attn_kernel(
    const short* __restrict__ Qb, const short* __restrict__ Kb,
    const short* __restrict__ VTb, unsigned short* __restrict__ Opart,
    float* __restrict__ zsum, int ksplit, int keys_per_split)
{
  __shared__ __align__(16) short kt2[2][BK * 256];   // 2 x 16KB [key][d]
  __shared__ __align__(16) short vt2[2][256 * BK];   // 2 x 16KB [d][key]
  __shared__ float zr[4];

  const int bid = blockIdx.x;
  const int ksl = bid % ksplit;                  // low bits -> XCD slice
  const int rb  = bid / ksplit;
  const int row0 = rb * 128;
  const int key0 = ksl * keys_per_split;
  const int ntiles = keys_per_split / BK;

  const int tid = threadIdx.x, wid = tid >> 6, lane = tid & 63;
  const int l15 = lane & 15, h = lane >> 4;
  const int wq0 = row0 + wid * 32;

  // Q fragments (B-operand of S^T mfma): q = wq0 + nq*16 + l15, d = kd*32+h*8+j
  short8 qf[2][8];
#pragma unroll
  for (int nq = 0; nq < 2; ++nq)
#pragma unroll
    for (int kd = 0; kd < 8; ++kd)
      qf[nq][kd] = *(const short8*)(Qb + (size_t)(wq0 + nq * 16 + l15) * CH + kd * 32 + h * 8);

  f32x4 oacc[2][16] = {};
  float zloc = 0.f;

  // bpermute source-lane addresses (byte = lane*4)
  const int addr0 = (l15 + ((h & 1) << 5)) << 2;   // lane l15 + 32*(h&1)
  const int addr1 = addr0 + 64;                    // +16 lanes
  const int hs = h >> 1;                           // source-register selector

  // staging helper indices (per thread: 4 K chunks + 4 VT chunks = 8 gloads)
  // K:  chunk g in [0,1024): r = g>>5 (key), clp = g&31; logical d-chunk = clp^(r&7)
  // VT: chunk g in [0,1024): d = g>>2, clp = g&3;  logical k-chunk = clp^((d>>1)&3)
#define STAGE_TILE(buf, kbase_)                                                 \
  {                                                                             \
    const int kbase = (kbase_);                                                 \
    _Pragma("unroll")                                                           \
    for (int i = 0; i < 4; ++i) {                                               \
      int g = i * 256 + tid;                                                    \
      int r = g >> 5, clp = g & 31;                                             \
      const short* src = Kb + (size_t)(kbase + r) * CH + (clp ^ (r & 7)) * 8;   \
      gload16(src, &kt2[buf][(i * 256 + wid * 64) * 8]);                        \
    }                                                                           \
    _Pragma("unroll")                                                           \
    for (int i = 0; i < 4; ++i) {                                               \
      int g = i * 256 + tid;                                                    \
      int d = g >> 2, clp = g & 3;                                              \
      const short* src = VTb + (size_t)d * LSEQ + kbase + (clp ^ ((d >> 1) & 3)) * 8; \
      gload16(src, &vt2[buf][(i * 256 + wid * 64) * 8]);                        \
    }                                                                           \
  }

#define COMPUTE_TILE(buf)                                                       \
  {                                                                             \
    const short* kt = kt2[buf];                                                 \
    const short* vt = vt2[buf];                                                 \
    f32x4 sacc[2][2] = {};                                                      \
    __builtin_amdgcn_s_setprio(1);                                              \
    _Pragma("unroll")                                                           \
    for (int kd = 0; kd < 8; ++kd) {                                            \
      _Pragma("unroll")                                                         \
      for (int mk2 = 0; mk2 < 2; ++mk2) {                                       \
        int key = mk2 * 16 + l15;                                               \
        short8 kf = *(const short8*)(&kt[key * CH + (((kd * 4 + h) ^ (l15 & 7)) * 8)]); \
        sacc[mk2][0] = mfma16(kf, qf[0][kd], sacc[mk2][0]);                     \
        sacc[mk2][1] = mfma16(kf, qf[1][kd], sacc[mk2][1]);                     \
      }                                                                         \
    }                                                                           \
    __builtin_amdgcn_s_setprio(0);                                              \
    u32 pk[2][2][2];                                                            \
    _Pragma("unroll")                                                           \
    for (int mk2 = 0; mk2 < 2; ++mk2)                                           \
      _Pragma("unroll")                                                         \
      for (int nq = 0; nq < 2; ++nq) {                                          \
        float p0 = __expf(sacc[mk2][nq][0]) - 1.0f;                             \
        float p1 = __expf(sacc[mk2][nq][1]) - 1.0f;                             \
        float p2 = __expf(sacc[mk2][nq][2]) - 1.0f;                             \
        float p3 = __expf(sacc[mk2][nq][3]) - 1.0f;                             \
        zloc += (p0 + p1) + (p2 + p3);                                          \
        pk[mk2][nq][0] = (u32)(unsigned short)f2bf(p0) | ((u32)(unsigned short)f2bf(p1) << 16); \
        pk[mk2][nq][1] = (u32)(unsigned short)f2bf(p2) | ((u32)(unsigned short)f2bf(p3) << 16); \
      }                                                                         \
    short8 PA[2];                                                               \
    _Pragma("unroll")                                                           \
    for (int nq = 0; nq < 2; ++nq) {                                            \
      u32 a00 = (u32)__builtin_amdgcn_ds_bpermute(addr0, (int)pk[0][nq][0]);    \
      u32 a01 = (u32)__builtin_amdgcn_ds_bpermute(addr0, (int)pk[1][nq][0]);    \
      u32 a10 = (u32)__builtin_amdgcn_ds_bpermute(addr0, (int)pk[0][nq][1]);    \
      u32 a11 = (u32)__builtin_amdgcn_ds_bpermute(addr0, (int)pk[1][nq][1]);    \
      u32 a20 = (u32)__builtin_amdgcn_ds_bpermute(addr1, (int)pk[0][nq][0]);    \
      u32 a21 = (u32)__builtin_amdgcn_ds_bpermute(addr1, (int)pk[1][nq][0]);    \
      u32 a30 = (u32)__builtin_amdgcn_ds_bpermute(addr1, (int)pk[0][nq][1]);    \
      u32 a31 = (u32)__builtin_amdgcn_ds_bpermute(addr1, (int)pk[1][nq][1]);    \
      union { u32 u[4]; short8 s; } cv;                                         \
      cv.u[0] = hs ? a01 : a00;                                                 \
      cv.u[1] = hs ? a11 : a10;                                                 \
      cv.u[2] = hs ? a21 : a20;                                                 \
      cv.u[3] = hs ? a31 : a30;                                                 \
      PA[nq] = cv.s;                                                            \
    }                                                                           \
    __builtin_amdgcn_s_setprio(1);                                              \
    _Pragma("unroll")                                                           \
    for (int nf2 = 0; nf2 < 16; ++nf2) {                                        \
      int d = nf2 * 16 + l15;                                                   \
      short8 vf = *(const short8*)(&vt[d * BK + ((h ^ ((d >> 1) & 3)) * 8)]);   \
      oacc[0][nf2] = mfma16(PA[0], vf, oacc[0][nf2]);                           \
      oacc[1][nf2] = mfma16(PA[1], vf, oacc[1][nf2]);                           \
    }                                                                           \
    __builtin_amdgcn_s_setprio(0);                                              \
  }

  // ---- T3 2-phase pipeline with counted vmcnt ----
  STAGE_TILE(0, key0);                       // prologue: tile 0 -> buf0
  for (int t = 0; t < ntiles - 1; ++t) {
    const int buf = t & 1;
    STAGE_TILE(buf ^ 1, key0 + (t + 1) * BK);          // prefetch t+1
    asm volatile("s_waitcnt vmcnt(8)" ::: "memory");   // tile t's 8 loads done
    __builtin_amdgcn_s_barrier();
    COMPUTE_TILE(buf);
    __builtin_amdgcn_s_barrier();            // readers done before t+2's DMA
  }
  asm volatile("s_waitcnt vmcnt(0)" ::: "memory");     // last tile staged
  __builtin_amdgcn_s_barrier();
  COMPUTE_TILE((ntiles - 1) & 1);

  // write partial O (bf16; disjoint per (rb, ksl))
  unsigned short* op = Opart + (size_t)ksl * LSEQ * CH;
#pragma unroll
  for (int nq = 0; nq < 2; ++nq)
#pragma unroll
    for (int nf2 = 0; nf2 < 16; ++nf2) {
      int col = nf2 * 16 + l15;
#pragma unroll
      for (int r = 0; r < 4; ++r) {
        int row = wq0 + nq * 16 + h * 4 + r;
        op[(size_t)row * CH + col] = (unsigned short)f2bf(oacc[nq][nf2][r]);
      }
    }

  // z: wave shuffle-reduce -> block reduce -> one atomic per block
#pragma unroll
  for (int off = 32; off > 0; off >>= 1) zloc += __shfl_down(zloc, off, 64);
  if (lane == 0) zr[wid] = zloc;
  __syncthreads();
  if (tid == 0) atomicAdd(zsum, (zr[0] + zr[1]) + (zr[2] + zr[3]));
}

// ---------------------------------------------------------------------------
// Kernel 3: O = (colsum(V) + sum_k Opart[k]) / (L^2 + zsum)
// ---------------------------------------------------------------------------
__global__ __launch_bounds__(256) void final_kernel(
    const unsigned short* __restrict__ Opart, const float* __restrict__ colsum,
    const float* __restrict__ zsum, float* __restrict__ out, int ksplit)
{
  size_t idx = (size_t)blockIdx.x * 256 + threadIdx.x;  // 4 outputs per thread
  float inv = 1.0f / (8192.0f * 8192.0f + *zsum);
  int col0 = (int)((idx * 4) & (CH - 1));
  float4 acc = *(const float4*)(colsum + col0);
  for (int k = 0; k < ksplit; ++k) {
    ushort4v p = *(const ushort4v*)(Opart + (size_t)k * LSEQ * CH + idx * 4);
    acc.x += bf2f(p[0]); acc.y += bf2f(p[1]);
    acc.z += bf2f(p[2]); acc.w += bf2f(p[3]);
  }
  float4 o;
  o.x = acc.x * inv; o.y = acc.y * inv; o.z = acc.z * inv; o.w = acc.w * inv;
  *(float4*)(out + idx * 4) = o;
}

// ---------------------------------------------------------------------------
extern "C" void kernel_launch(void* const* d_in, const int* in_sizes, int n_in,
                              void* d_out, int out_size, void* d_ws, size_t ws_size,
                              hipStream_t stream) {
  const float* x  = (const float*)d_in[0];
  const float* Wq = (const float*)d_in[1];
  const float* bq = (const float*)d_in[2];
  const float* Wk = (const float*)d_in[3];
  const float* bk = (const float*)d_in[4];
  const float* Wv = (const float*)d_in[5];
  const float* bv = (const float*)d_in[6];
  float* out = (float*)d_out;

  // workspace layout
  char* ws = (char*)d_ws;
  short* Qb  = (short*)ws;                                   // 4 MB
  short* Kb  = Qb + (size_t)LSEQ * CH;                       // 4 MB
  short* VTb = Kb + (size_t)LSEQ * CH;                       // 4 MB
  float* colsum = (float*)(VTb + (size_t)CH * LSEQ);         // 1 KB
  float* zsum   = (float*)((char*)colsum + 2048);            // 4 B
  unsigned short* Opart = (unsigned short*)((char*)ws + 12u * 1024 * 1024 + 4096);
  const size_t fixed = 12u * 1024 * 1024 + 4096;
  const size_t part_bytes = (size_t)LSEQ * CH * sizeof(unsigned short);  // 4 MB

  int ksplit = 8;  // key-split: blockIdx%8 -> XCD -> L2-resident K/VT slice
  while (ksplit > 1 && fixed + (size_t)ksplit * part_bytes > ws_size) ksplit >>= 1;

  hipMemsetAsync(zsum, 0, sizeof(float), stream);

  qkv_kernel<<<dim3(512, 3), 256, 0, stream>>>(x, Wq, bq, Wk, bk, Wv, bv,
                                               Qb, Kb, VTb);
  colsum_kernel<<<CH, 256, 0, stream>>>(VTb, colsum);
  attn_kernel<<<(LSEQ / 128) * ksplit, 256, 0, stream>>>(
      Qb, Kb, VTb, Opart, zsum, ksplit, LSEQ / ksplit);
  final_kernel<<<(LSEQ * CH / 4) / 256, 256, 0, stream>>>(
      Opart, colsum, zsum, out, ksplit);
}